// Round 18
// baseline (122.905 us; speedup 1.0000x reference)
//
#include <hip/hip_runtime.h>
#include <hip/hip_bf16.h>
#include <hip/hip_fp16.h>

#define GG 8
#define AA 65
#define BB 256

typedef __attribute__((ext_vector_type(8))) short bf16x8;
typedef __attribute__((ext_vector_type(4))) short s16x4;
typedef __attribute__((ext_vector_type(4))) float f32x4;
typedef _Float16 hf2 __attribute__((ext_vector_type(2)));
#define MFMA16(a, b, c) __builtin_amdgcn_mfma_f32_16x16x32_bf16(a, b, c, 0, 0, 0)
#define FDOT2(a, b, c) __builtin_amdgcn_fdot2((a), (b), (c), false)

__device__ __forceinline__ void rz_taps(int o, float scale, int in_size,
                                        int& ia, int& ib, float& f) {
  float pos = (o + 0.5f) * scale - 0.5f;
  float fl = floorf(pos);
  int i0 = (int)fl;
  f = pos - fl;
  ia = i0 < 0 ? 0 : i0;
  int i1 = i0 + 1;
  ib = i1 > (in_size - 1) ? (in_size - 1) : i1;
}

// Compile-time 128->65 tap: pos = (j+0.5)*65/128-0.5 = (130j-63)/256 exactly.
#define JTAP(jc, ja, jb, fj) \
  const int num_ = 130 * (jc) - 63;               \
  const int fl_ = num_ >> 8;                      \
  const int ja = fl_ < 0 ? 0 : fl_;               \
  const int jb = (fl_ + 1 > 64) ? 64 : (fl_ + 1); \
  const float fj = (float)(num_ - (fl_ << 8)) * 0.00390625f;

__device__ __forceinline__ float gelu_exact(float v) {
  return 0.5f * v * (1.0f + erff(v * 0.70710678118654752f));
}

__device__ __forceinline__ short f2b(float f) {
  __hip_bfloat16 h = __float2bfloat16(f);
  return *reinterpret_cast<short*>(&h);
}
__device__ __forceinline__ float b2f(short s) {
  unsigned int u = ((unsigned int)(unsigned short)s) << 16;
  return __uint_as_float(u);
}

#define RSBN 0.99999500003749977f  // 1/sqrt(1+1e-5)

// ---------- PREP: weights->bf16, relA2/relAT2 (fp16 c-pair packed), veA4 ----------
__global__ void k_prep(const float* __restrict__ base, const float* __restrict__ wq,
                       const float* __restrict__ w1, const float* __restrict__ w2,
                       short* __restrict__ wqb, short* __restrict__ w1b,
                       short* __restrict__ w2b, __half* __restrict__ relA2h,
                       __half* __restrict__ relAT2h, __half* __restrict__ veA4) {
  int blk = blockIdx.x;
  int tt = threadIdx.x;
  if (blk < 256) {             // weights
    int i = blk * 256 + tt;
    if (i < 32768) wqb[i] = f2b(wq[i]);
    w1b[i] = f2b(w1[i]);
    w2b[i] = f2b(w2[i]);
    return;
  }
  blk -= 256;
  if (blk < 265) {             // q_emb / k_emb^T, fp16 c-pair dword layout [cp][i][68]
    int idx = blk * 256 + tt;
    if (idx >= 16 * AA * AA) return;
    int j = idx % AA;
    int r = idx / AA;
    int i = r % AA;
    int c = r / AA;
    int ia, ib, ja, jb; float fi, fj;
    rz_taps(i, 255.0f / 65.0f, 255, ia, ib, fi);
    rz_taps(j, 255.0f / 65.0f, 255, ja, jb, fj);
    const float* S = base + (size_t)c * 255 * 255;
    float v = (1.0f - fi) * ((1.0f - fj) * S[ia * 255 + ja] + fj * S[ia * 255 + jb])
            + fi * ((1.0f - fj) * S[ib * 255 + ja] + fj * S[ib * 255 + jb]);
    if (c < 8) {
      relA2h[((((c >> 1) * 4420) + i * 68 + j) << 1) + (c & 1)] = __float2half(v);
    } else {
      int c2 = c - 8;
      relAT2h[((((c2 >> 1) * 4420) + j * 68 + i) << 1) + (c2 & 1)] = __float2half(v);
    }
    return;
  }
  blk -= 265;
  {  // veA4[c][ap4][i] float4-groups (8 halves = 8 a's); wave-coalesced AND x4-vector
    int idx = blk * 256 + tt;  // 16*72*128 = 147,456
    if (idx >= 16 * 72 * 128) return;
    int i = idx & 127;
    int r = idx >> 7;
    int a = r % 72, c = r / 72;
    float v = 0.f;
    if (a < 65) {
      int ia, ib; float fi;
      rz_taps(i, 65.0f / 128.0f, 65, ia, ib, fi);
      int ja, jb; float fj;
      rz_taps(a, 255.0f / 65.0f, 255, ja, jb, fj);
      int p0a, p0b; float g0;
      rz_taps(ia, 255.0f / 65.0f, 255, p0a, p0b, g0);
      int p1a, p1b; float g1;
      rz_taps(ib, 255.0f / 65.0f, 255, p1a, p1b, g1);
      const float* S = base + (size_t)(16 + c) * 255 * 255;
      float r0 = (1.0f - g0) * ((1.0f - fj) * S[p0a * 255 + ja] + fj * S[p0a * 255 + jb])
               + g0 * ((1.0f - fj) * S[p0b * 255 + ja] + fj * S[p0b * 255 + jb]);
      float r1 = (1.0f - g1) * ((1.0f - fj) * S[p1a * 255 + ja] + fj * S[p1a * 255 + jb])
               + g1 * ((1.0f - fj) * S[p1b * 255 + ja] + fj * S[p1b * 255 + jb]);
      v = (1.0f - fi) * r0 + fi * r1;
    }
    veA4[(((size_t)(c * 9 + (a >> 3)) * 128 + i) << 3) + (a & 7)] = __float2half(v);
  }
}

// ---------- MFMA GEMM 1: qkva[n][o][a][w] = bf16(BN(Wqkv . downsample_i(x))) ----------
__global__ __launch_bounds__(256) void k_qkv_mfma(
    const float* __restrict__ x, const short* __restrict__ wqb,
    const float* __restrict__ bg, const float* __restrict__ bb,
    short* __restrict__ out) {
  const int ob = blockIdx.x * 128;
  const int ya = blockIdx.y;           // a*2 + p-half
  const int a = ya >> 1;
  const int pb = (ya & 1) * 64;
  const int n = blockIdx.z;
  __shared__ short Asm[128 * 40];
  __shared__ short Bsm[64 * 40];
  const int t = threadIdx.x;
  const int lane = t & 63, wv = t >> 6;
  const int wm = wv >> 1, wn = wv & 1;
  const int lr = lane & 15, lk = (lane >> 4) * 8;
  int ia, ib; float f;
  rz_taps(a, 128.0f / 65.0f, 128, ia, ib, f);
  const float f0 = 1.0f - f;
  f32x4 acc[4][2];
  #pragma unroll
  for (int i = 0; i < 4; ++i)
    #pragma unroll
    for (int j = 0; j < 2; ++j)
      #pragma unroll
      for (int q = 0; q < 4; ++q) acc[i][j][q] = 0.f;
  const float* X = x + (size_t)n * 128 * 16384;
  for (int k0 = 0; k0 < 128; k0 += 32) {
    #pragma unroll
    for (int i2 = 0; i2 < 2; ++i2) {
      int u = t + 256 * i2;
      int row = u >> 2, kq = (u & 3) * 8;
      *(bf16x8*)&Asm[row * 40 + kq] = *(const bf16x8*)&wqb[(ob + row) * 128 + k0 + kq];
    }
    {
      int k = t >> 3, p8 = (t & 7) * 8;
      int c = k0 + k;
      const float* rowA = X + ((size_t)c * 128 + ia) * 128 + pb + p8;
      const float* rowB = X + ((size_t)c * 128 + ib) * 128 + pb + p8;
      float4 a0 = *(const float4*)rowA;
      float4 a1 = *(const float4*)(rowA + 4);
      float4 b0 = *(const float4*)rowB;
      float4 b1 = *(const float4*)(rowB + 4);
      short* d = &Bsm[p8 * 40 + k];
      d[0 * 40] = f2b(f0 * a0.x + f * b0.x);
      d[1 * 40] = f2b(f0 * a0.y + f * b0.y);
      d[2 * 40] = f2b(f0 * a0.z + f * b0.z);
      d[3 * 40] = f2b(f0 * a0.w + f * b0.w);
      d[4 * 40] = f2b(f0 * a1.x + f * b1.x);
      d[5 * 40] = f2b(f0 * a1.y + f * b1.y);
      d[6 * 40] = f2b(f0 * a1.z + f * b1.z);
      d[7 * 40] = f2b(f0 * a1.w + f * b1.w);
    }
    __syncthreads();
    bf16x8 af[4], bfr[2];
    #pragma unroll
    for (int mf = 0; mf < 4; ++mf) af[mf] = *(bf16x8*)&Asm[(wm * 64 + mf * 16 + lr) * 40 + lk];
    #pragma unroll
    for (int nf = 0; nf < 2; ++nf) bfr[nf] = *(bf16x8*)&Bsm[(wn * 32 + nf * 16 + lr) * 40 + lk];
    #pragma unroll
    for (int mf = 0; mf < 4; ++mf)
      #pragma unroll
      for (int nf = 0; nf < 2; ++nf)
        acc[mf][nf] = MFMA16(af[mf], bfr[nf], acc[mf][nf]);
    __syncthreads();
  }
  #pragma unroll
  for (int mf = 0; mf < 4; ++mf) {
    #pragma unroll
    for (int r = 0; r < 4; ++r) {
      int o = ob + wm * 64 + mf * 16 + (lane >> 4) * 4 + r;
      float sc = bg[o] * RSBN, sh = bb[o];
      #pragma unroll
      for (int nf = 0; nf < 2; ++nf) {
        int p = pb + wn * 32 + nf * 16 + lr;
        out[((size_t)(n * 256 + o) * 65 + a) * 128 + p] = f2b(acc[mf][nf][r] * sc + sh);
      }
    }
  }
}

// ---------- F: fused sim(fp16 dot2) + softmax + x4-dot2 sv/sve + bn_out ----------
// Pinv lives in the spare tail of Ss (beyond PwsH) -> LDS 20,480 B = 8 blocks/CU.
__global__ void k_attn(const short* __restrict__ qkva, const __half* __restrict__ relA2,
                       const __half* __restrict__ relAT2, const __half* __restrict__ veA4,
                       const float* __restrict__ sg, const float* __restrict__ sb,
                       const float* __restrict__ og, const float* __restrict__ ob,
                       float* __restrict__ yT) {
  int orig = blockIdx.x;
  int bg = ((orig & 7) << 8) + (orig >> 3);  // bijective XCD-chunk swizzle
  int b = bg >> 3, g = bg & 7;
  int n = b >> 7, w = b & 127;
  __shared__ __attribute__((aligned(16))) float Ss[65 * 68];  // 17,680 B; PwsH+Pinv after
  __shared__ __attribute__((aligned(16))) float u0[576];      // 2,304 B
  __half* PwsH = (__half*)Ss;            // 128*66 halves = 16,896 B
  float* Pinv2 = Ss + 4224;              // floats 4224..4351 (beyond PwsH, within Ss)
  hf2* qs2 = (hf2*)u0;
  hf2* ks2v = (hf2*)(u0 + 260);
  float* ks2f = u0 + 260;
  __half* vasH = (__half*)u0;
  int t = threadIdx.x;
  const short* Qbase = qkva + ((size_t)(n * 256 + g * 32) * 65) * 128 + w;

  // phase 1: stage q,k as fp16 c-pairs
  for (int l = t; l < 520; l += 256) {
    int isQ = (l < 260);
    int u2 = isQ ? l : l - 260;
    int cp = u2 / 65, a = u2 - cp * 65;
    int cbase = (cp << 1) + (isQ ? 0 : 8);
    float v0 = b2f(Qbase[(size_t)(cbase * 65 + a) * 128]);
    float v1 = b2f(Qbase[(size_t)((cbase + 1) * 65 + a) * 128]);
    hf2 h;
    h[0] = (_Float16)v0;
    h[1] = (_Float16)v1;
    if (isQ) qs2[cp * 65 + a] = h;
    else ks2v[cp * 68 + a] = h;
  }
  __syncthreads();

  // phase 2: sim 65x65 via packed fdot2 (qk+qr+kr, BN-combined)
  {
    float sqk = sg[g] * RSBN, sqr = sg[8 + g] * RSBN, skr = sg[16 + g] * RSBN;
    float badd = sb[g] + sb[8 + g] + sb[16 + g];
    const float* rAf = (const float*)relA2;
    const float* rTf = (const float*)relAT2;
    const hf2* rAv = (const hf2*)relA2;
    const hf2* rTv = (const hf2*)relAT2;
    for (int u = t; u < 65 * 17; u += 256) {
      int i = u / 17, jq = u - i * 17;
      hf2 q2[4];
      #pragma unroll
      for (int cp = 0; cp < 4; ++cp) q2[cp] = qs2[cp * 65 + i];
      if (jq < 16) {
        int j0 = jq * 4;
        int lofs = i * 68 + j0;
        float qk0 = 0, qk1 = 0, qk2 = 0, qk3 = 0;
        float qr0 = 0, qr1 = 0, qr2 = 0, qr3 = 0;
        float kr0 = 0, kr1 = 0, kr2 = 0, kr3 = 0;
        #pragma unroll
        for (int cp = 0; cp < 4; ++cp) {
          float4 kq = *(const float4*)&ks2f[cp * 68 + j0];
          float4 ra = *(const float4*)&rAf[cp * 4420 + lofs];
          float4 rt = *(const float4*)&rTf[cp * 4420 + lofs];
          hf2 k0 = __builtin_bit_cast(hf2, kq.x);
          hf2 k1 = __builtin_bit_cast(hf2, kq.y);
          hf2 k2h = __builtin_bit_cast(hf2, kq.z);
          hf2 k3 = __builtin_bit_cast(hf2, kq.w);
          qk0 = FDOT2(k0, q2[cp], qk0);
          qk1 = FDOT2(k1, q2[cp], qk1);
          qk2 = FDOT2(k2h, q2[cp], qk2);
          qk3 = FDOT2(k3, q2[cp], qk3);
          qr0 = FDOT2(__builtin_bit_cast(hf2, ra.x), q2[cp], qr0);
          qr1 = FDOT2(__builtin_bit_cast(hf2, ra.y), q2[cp], qr1);
          qr2 = FDOT2(__builtin_bit_cast(hf2, ra.z), q2[cp], qr2);
          qr3 = FDOT2(__builtin_bit_cast(hf2, ra.w), q2[cp], qr3);
          kr0 = FDOT2(__builtin_bit_cast(hf2, rt.x), k0, kr0);
          kr1 = FDOT2(__builtin_bit_cast(hf2, rt.y), k1, kr1);
          kr2 = FDOT2(__builtin_bit_cast(hf2, rt.z), k2h, kr2);
          kr3 = FDOT2(__builtin_bit_cast(hf2, rt.w), k3, kr3);
        }
        float4 res;
        res.x = sqk * qk0 + sqr * qr0 + skr * kr0 + badd;
        res.y = sqk * qk1 + sqr * qr1 + skr * kr1 + badd;
        res.z = sqk * qk2 + sqr * qr2 + skr * kr2 + badd;
        res.w = sqk * qk3 + sqr * qr3 + skr * kr3 + badd;
        *(float4*)&Ss[lofs] = res;
      } else {
        int lofs = i * 68 + 64;
        float qk = 0, qr = 0, kr = 0;
        #pragma unroll
        for (int cp = 0; cp < 4; ++cp) {
          hf2 kv = ks2v[cp * 68 + 64];
          qk = FDOT2(kv, q2[cp], qk);
          qr = FDOT2(rAv[cp * 4420 + lofs], q2[cp], qr);
          kr = FDOT2(rTv[cp * 4420 + lofs], kv, kr);
        }
        Ss[lofs] = sqk * qk + sqr * qr + skr * kr + badd;
      }
    }
  }
  __syncthreads();

  // phase 3: v stage (fp16, a padded to 72, overlays u0) + register-T softmax fold
  for (int l = t; l < 16 * 72; l += 256) {
    int c = l / 72, a = l - c * 72;
    float v = (a < 65) ? b2f(Qbase[(size_t)((16 + c) * 65 + a) * 128]) : 0.f;
    vasH[l] = __float2half(v);
  }
  {
    const int i = t >> 1, h = t & 1;
    int ia, ib; float fi;
    rz_taps(i, 65.0f / 128.0f, 65, ia, ib, fi);
    const float* r0 = Ss + ia * 68 + h * 32;
    const float* r1 = Ss + ib * 68 + h * 32;
    const float wi0 = 1.0f - fi;
    float T[33];
    #pragma unroll
    for (int k4 = 0; k4 < 8; ++k4) {
      float4 a4 = *(const float4*)(r0 + 4 * k4);
      float4 b4 = *(const float4*)(r1 + 4 * k4);
      T[4 * k4 + 0] = wi0 * a4.x + fi * b4.x;
      T[4 * k4 + 1] = wi0 * a4.y + fi * b4.y;
      T[4 * k4 + 2] = wi0 * a4.z + fi * b4.z;
      T[4 * k4 + 3] = wi0 * a4.w + fi * b4.w;
    }
    T[32] = wi0 * r0[32] + fi * r1[32];
    float mx = T[0];
    #pragma unroll
    for (int k = 1; k < 33; ++k) mx = fmaxf(mx, T[k]);
    mx = fmaxf(mx, __shfl_xor(mx, 1));
    float p[33];
    #pragma unroll
    for (int k = 0; k < 33; ++k) p[k] = 0.f;
    float sum = 0.f;
    if (h == 0) {
      #pragma unroll
      for (int j = 0; j < 64; ++j) {
        JTAP(j, ja, jb, fj);
        float v = (1.0f - fj) * T[ja] + fj * T[jb];
        float e = __expf(v - mx);
        sum += e;
        p[ja] += e * (1.0f - fj);
        p[jb] += e * fj;
      }
    } else {
      #pragma unroll
      for (int j = 64; j < 128; ++j) {
        JTAP(j, ja, jb, fj);
        float v = (1.0f - fj) * T[ja - 32] + fj * T[jb - 32];
        float e = __expf(v - mx);
        sum += e;
        p[ja - 32] += e * (1.0f - fj);
        p[jb - 32] += e * fj;
      }
    }
    sum += __shfl_xor(sum, 1);
    float other = __shfl_xor(h ? p[0] : p[32], 1);
    __syncthreads();   // all Ss reads complete before Pw/Pinv overwrite the same LDS
    __half* prow = &PwsH[i * 66];
    if (h == 0) {
      p[32] += other;
      #pragma unroll
      for (int k = 0; k < 33; ++k) prow[k] = __float2half(p[k]);
      Pinv2[i] = 1.0f / sum;
    } else {
      p[0] += other;
      #pragma unroll
      for (int k = 0; k < 33; ++k) prow[32 + k] = __float2half(p[k]);
      prow[65] = __float2half(0.f);
    }
  }
  __syncthreads();

  // phase 4: x4-vectorized dot2 (float4 LDS vas + float4 coalesced veA4)
  {
    const int i = t & 127;
    const int cg = t >> 7;
    const float inv = Pinv2[i];
    hf2 pw[33];
    const hf2* prow2 = (const hf2*)&PwsH[i * 66];
    #pragma unroll
    for (int ap = 0; ap < 33; ++ap) pw[ap] = prow2[ap];
    #pragma unroll
    for (int l = 0; l < 8; ++l) {
      const int c = cg * 8 + l;
      const float4* vr4 = (const float4*)&vasH[c * 72];
      const float4* vp4 = (const float4*)veA4 + (size_t)(c * 9) * 128 + i;
      float sv0 = 0.f, sv1 = 0.f, se0 = 0.f, se1 = 0.f;
      #pragma unroll
      for (int q4 = 0; q4 < 8; ++q4) {
        float4 a4 = vr4[q4];
        float4 b4 = vp4[(size_t)q4 * 128];
        sv0 = FDOT2(__builtin_bit_cast(hf2, a4.x), pw[4 * q4 + 0], sv0);
        sv1 = FDOT2(__builtin_bit_cast(hf2, a4.y), pw[4 * q4 + 1], sv1);
        sv0 = FDOT2(__builtin_bit_cast(hf2, a4.z), pw[4 * q4 + 2], sv0);
        sv1 = FDOT2(__builtin_bit_cast(hf2, a4.w), pw[4 * q4 + 3], sv1);
        se0 = FDOT2(__builtin_bit_cast(hf2, b4.x), pw[4 * q4 + 0], se0);
        se1 = FDOT2(__builtin_bit_cast(hf2, b4.y), pw[4 * q4 + 1], se1);
        se0 = FDOT2(__builtin_bit_cast(hf2, b4.z), pw[4 * q4 + 2], se0);
        se1 = FDOT2(__builtin_bit_cast(hf2, b4.w), pw[4 * q4 + 3], se1);
      }
      {  // tail: ap=32
        float4 a4 = vr4[8];
        float4 b4 = vp4[(size_t)8 * 128];
        sv0 = FDOT2(__builtin_bit_cast(hf2, a4.x), pw[32], sv0);
        se0 = FDOT2(__builtin_bit_cast(hf2, b4.x), pw[32], se0);
      }
      float sv = sv0 + sv1, se = se0 + se1;
      int c2 = g * 16 + c;
      int o0 = 2 * c2;
      float val = og[o0] * RSBN * (sv * inv) + ob[o0]
                + og[o0 + 1] * RSBN * (se * inv) + ob[o0 + 1];
      yT[((size_t)(n * 128 + c2)) * 16384 + w * 128 + i] = val;
    }
  }
}

// ---------- XS: stage yT plane (fp32 LDS), emit xnb (shift+IN, bf16) + yStd (fp32) ----------
__global__ __launch_bounds__(256) void k_xs(const float* __restrict__ yT,
                                            const float* __restrict__ inw,
                                            const float* __restrict__ inb,
                                            short* __restrict__ xnb,
                                            float* __restrict__ yStd) {
  int gid = blockIdx.x;
  int n, cs, cx = -1;
  bool wStd;
  if (gid < 256) {
    n = gid >> 7; cx = gid & 127;
    cs = (cx < 40) ? (cx % 10) : cx;
    wStd = (cx < 10) || (cx >= 40);
  } else {
    int u = gid - 256;
    n = u / 30; cs = 10 + (u % 30);
    wStd = true;
  }
  int dh = 0, dw = 0;
  if (cx >= 0) {
    if (cx < 10)       dw = -2;
    else if (cx < 20)  dw = 2;
    else if (cx < 30)  dh = -2;
    else if (cx < 40)  dh = 2;
  }
  __shared__ float Sb[128 * 130];
  __shared__ float sm[8];
  const float* src = yT + ((size_t)(n * 128 + cs)) * 16384;
  int t = threadIdx.x;
  #pragma unroll
  for (int l = 0; l < 16; ++l) {
    int q = t + l * 256;
    float4 v = *(const float4*)&src[q * 4];
    int w = q >> 5, i0 = (q * 4) & 127;
    float* d = &Sb[w * 130 + i0];
    *(float2*)d = make_float2(v.x, v.y);
    *(float2*)(d + 2) = make_float2(v.z, v.w);
  }
  __syncthreads();
  if (wStd) {
    float* dst = yStd + ((size_t)(n * 128 + cs)) * 16384;
    for (int l = 0; l < 64; ++l) {
      int idx = t + l * 256;
      int h = idx >> 7, w = idx & 127;
      dst[idx] = Sb[w * 130 + h];
    }
  }
  if (cx >= 0) {
    float s = 0.f, q2 = 0.f;
    for (int l = 0; l < 64; ++l) {
      int idx = t + l * 256;
      int h = idx >> 7, w = idx & 127;
      int hs = h + dh, ws = w + dw;
      float v = (hs >= 0 && hs < 128 && ws >= 0 && ws < 128) ? Sb[ws * 130 + hs] : 0.f;
      s += v; q2 += v * v;
    }
    #pragma unroll
    for (int o = 32; o; o >>= 1) { s += __shfl_down(s, o); q2 += __shfl_down(q2, o); }
    if ((t & 63) == 0) { sm[(t >> 6) * 2] = s; sm[(t >> 6) * 2 + 1] = q2; }
    __syncthreads();
    float S_ = sm[0] + sm[2] + sm[4] + sm[6];
    float Q_ = sm[1] + sm[3] + sm[5] + sm[7];
    float mean = S_ * (1.0f / 16384.0f);
    float var = Q_ * (1.0f / 16384.0f) - mean * mean;
    float scale = inw[cx] * rsqrtf(var + 1e-5f);
    float shift = inb[cx] - mean * scale;
    short* dst = xnb + ((size_t)(n * 128 + cx)) * 16384;
    for (int l = 0; l < 64; ++l) {
      int idx = t + l * 256;
      int h = idx >> 7, w = idx & 127;
      int hs = h + dh, ws = w + dw;
      float v = (hs >= 0 && hs < 128 && ws >= 0 && ws < 128) ? Sb[ws * 130 + hs] : 0.f;
      dst[idx] = f2b(v * scale + shift);
    }
  }
}

// ---------- FUSED MLP: out = W2 . gelu(W1 . xn) + yStd; 32-pixel tiles (4 blocks/CU) ----------
__global__ __launch_bounds__(256) void k_mlp(
    const short* __restrict__ xnb, const short* __restrict__ w1b,
    const short* __restrict__ w2b, const float* __restrict__ y,
    float* __restrict__ out) {
  const int pb = blockIdx.x * 32;
  const int n = blockIdx.z;
  __shared__ short Asm[128 * 40];      // 10,240 B: w1/w2 chunk staging
  __shared__ short Bxn[32 * 136];      // 8,704 B: xn [p][c], persistent
  __shared__ short h1s[32 * 136];      // 8,704 B: h1 chunk [p][o]
  const int t = threadIdx.x;
  const int lane = t & 63, wv = t >> 6;
  const int wm = wv >> 1, wn = wv & 1;
  const int lr = lane & 15, lk = (lane >> 4) * 8;
  const short* X = xnb + (size_t)n * 128 * 16384;
  // stage xn once: [32 p][136-pad c]
  #pragma unroll
  for (int i2 = 0; i2 < 2; ++i2) {
    int u = t + 256 * i2;               // 512: c = u>>2, p0 = (u&3)*8
    int c = u >> 2, p0 = (u & 3) * 8;
    bf16x8 hv = *(const bf16x8*)&X[(size_t)c * 16384 + pb + p0];
    #pragma unroll
    for (int j = 0; j < 8; ++j) Bxn[(p0 + j) * 136 + c] = hv[j];
  }
  f32x4 acc2[4][1];
  #pragma unroll
  for (int i = 0; i < 4; ++i)
    #pragma unroll
    for (int q = 0; q < 4; ++q) acc2[i][0][q] = 0.f;
  __syncthreads();

  for (int och = 0; och < 4; ++och) {
    // ---- GEMM1: h1c[128 o][32 p] = w1[och] . xn ----
    f32x4 acc1[4][1];
    #pragma unroll
    for (int i = 0; i < 4; ++i)
      #pragma unroll
      for (int q = 0; q < 4; ++q) acc1[i][0][q] = 0.f;
    for (int c0 = 0; c0 < 128; c0 += 32) {
      #pragma unroll
      for (int i2 = 0; i2 < 2; ++i2) {
        int u = t + 256 * i2;
        int row = u >> 2, kq = (u & 3) * 8;
        *(bf16x8*)&Asm[row * 40 + kq] =
            *(const bf16x8*)&w1b[(och * 128 + row) * 128 + c0 + kq];
      }
      __syncthreads();
      bf16x8 af[4], bfr;
      #pragma unroll
      for (int mf = 0; mf < 4; ++mf)
        af[mf] = *(bf16x8*)&Asm[(wm * 64 + mf * 16 + lr) * 40 + lk];
      bfr = *(bf16x8*)&Bxn[(wn * 16 + lr) * 136 + c0 + lk];
      #pragma unroll
      for (int mf = 0; mf < 4; ++mf)
        acc1[mf][0] = MFMA16(af[mf], bfr, acc1[mf][0]);
      __syncthreads();
    }
    // ---- gelu -> h1s[p][o] (bf16) ----
    #pragma unroll
    for (int mf = 0; mf < 4; ++mf)
      #pragma unroll
      for (int r = 0; r < 4; ++r) {
        int o = wm * 64 + mf * 16 + (lane >> 4) * 4 + r;
        int p = wn * 16 + lr;
        h1s[p * 136 + o] = f2b(gelu_exact(acc1[mf][0][r]));
      }
    // ---- GEMM2: acc2 += w2[:, och-chunk] . h1s ----
    for (int k0 = 0; k0 < 128; k0 += 32) {
      #pragma unroll
      for (int i2 = 0; i2 < 2; ++i2) {
        int u = t + 256 * i2;
        int row = u >> 2, kq = (u & 3) * 8;
        *(bf16x8*)&Asm[row * 40 + kq] =
            *(const bf16x8*)&w2b[row * 512 + och * 128 + k0 + kq];
      }
      __syncthreads();
      bf16x8 af[4], bfr;
      #pragma unroll
      for (int mf = 0; mf < 4; ++mf)
        af[mf] = *(bf16x8*)&Asm[(wm * 64 + mf * 16 + lr) * 40 + lk];
      bfr = *(bf16x8*)&h1s[(wn * 16 + lr) * 136 + k0 + lk];
      #pragma unroll
      for (int mf = 0; mf < 4; ++mf)
        acc2[mf][0] = MFMA16(af[mf], bfr, acc2[mf][0]);
      __syncthreads();
    }
  }
  #pragma unroll
  for (int mf = 0; mf < 4; ++mf)
    #pragma unroll
    for (int r = 0; r < 4; ++r) {
      int o = wm * 64 + mf * 16 + (lane >> 4) * 4 + r;
      int p = pb + wn * 16 + lr;
      size_t base = ((size_t)(n * 128 + o)) * 16384 + p;
      out[base] = acc2[mf][0][r] + y[base];
    }
}

extern "C" void kernel_launch(void* const* d_in, const int* in_sizes, int n_in,
                              void* d_out, int out_size, void* d_ws, size_t ws_size,
                              hipStream_t stream) {
  const float* x        = (const float*)d_in[0];
  const float* w_qkv    = (const float*)d_in[1];
  const float* bn_qkv_g = (const float*)d_in[2];
  const float* bn_qkv_b = (const float*)d_in[3];
  const float* bn_sim_g = (const float*)d_in[4];
  const float* bn_sim_b = (const float*)d_in[5];
  const float* bn_out_g = (const float*)d_in[6];
  const float* bn_out_b = (const float*)d_in[7];
  const float* in_w     = (const float*)d_in[8];
  const float* in_b     = (const float*)d_in[9];
  const float* mlp_w1   = (const float*)d_in[10];
  const float* mlp_w2   = (const float*)d_in[11];
  const float* base_rel = (const float*)d_in[12];
  float* Wp = (float*)d_ws;

  __half* relA2  = (__half*)(Wp + 0);        // 17,680 f
  __half* relAT2 = (__half*)(Wp + 17680);    // 17,680 f
  __half* veA4   = (__half*)(Wp + 35360);    // 147,456 halves = 73,728 f
  float* yT      = Wp + 109088;              // 4,194,304
  float* yStd    = Wp + 4303392;             // 4,194,304
  short* wqb     = (short*)(Wp + 8497696);   // 32,768 shorts
  short* w1b     = (short*)(Wp + 8514080);   // 65,536 shorts
  short* w2b     = (short*)(Wp + 8546848);   // 65,536 shorts
  short* xnb     = (short*)(Wp + 8579616);   // 4,194,304 shorts
  short* qkva    = (short*)(Wp + 10676768);  // 4,259,840 shorts
  // peak: 12,806,688 floats = 51.2 MB

  k_prep<<<dim3(1097), dim3(256), 0, stream>>>(base_rel, w_qkv, mlp_w1, mlp_w2,
                                               wqb, w1b, w2b, relA2, relAT2, veA4);
  k_qkv_mfma<<<dim3(2, 130, 2), dim3(256), 0, stream>>>(x, wqb, bn_qkv_g, bn_qkv_b, qkva);
  k_attn<<<dim3(2048), dim3(256), 0, stream>>>(qkva, relA2, relAT2, veA4,
                                               bn_sim_g, bn_sim_b, bn_out_g, bn_out_b, yT);
  k_xs<<<dim3(316), dim3(256), 0, stream>>>(yT, in_w, in_b, xnb, yStd);
  k_mlp<<<dim3(512, 1, 2), dim3(256), 0, stream>>>(xnb, w1b, w2b, yStd, (float*)d_out);
}

// Round 19
// 114.552 us; speedup vs baseline: 1.0729x; 1.0729x over previous
//
#include <hip/hip_runtime.h>
#include <hip/hip_bf16.h>
#include <hip/hip_fp16.h>

#define GG 8
#define AA 65
#define BB 256

typedef __attribute__((ext_vector_type(8))) short bf16x8;
typedef __attribute__((ext_vector_type(4))) short s16x4;
typedef __attribute__((ext_vector_type(4))) float f32x4;
typedef _Float16 hf2 __attribute__((ext_vector_type(2)));
#define MFMA16(a, b, c) __builtin_amdgcn_mfma_f32_16x16x32_bf16(a, b, c, 0, 0, 0)
#define FDOT2(a, b, c) __builtin_amdgcn_fdot2((a), (b), (c), false)

__device__ __forceinline__ void rz_taps(int o, float scale, int in_size,
                                        int& ia, int& ib, float& f) {
  float pos = (o + 0.5f) * scale - 0.5f;
  float fl = floorf(pos);
  int i0 = (int)fl;
  f = pos - fl;
  ia = i0 < 0 ? 0 : i0;
  int i1 = i0 + 1;
  ib = i1 > (in_size - 1) ? (in_size - 1) : i1;
}

// Compile-time 128->65 tap: pos = (j+0.5)*65/128-0.5 = (130j-63)/256 exactly.
#define JTAP(jc, ja, jb, fj) \
  const int num_ = 130 * (jc) - 63;               \
  const int fl_ = num_ >> 8;                      \
  const int ja = fl_ < 0 ? 0 : fl_;               \
  const int jb = (fl_ + 1 > 64) ? 64 : (fl_ + 1); \
  const float fj = (float)(num_ - (fl_ << 8)) * 0.00390625f;

__device__ __forceinline__ float gelu_exact(float v) {
  return 0.5f * v * (1.0f + erff(v * 0.70710678118654752f));
}

__device__ __forceinline__ short f2b(float f) {
  __hip_bfloat16 h = __float2bfloat16(f);
  return *reinterpret_cast<short*>(&h);
}
__device__ __forceinline__ float b2f(short s) {
  unsigned int u = ((unsigned int)(unsigned short)s) << 16;
  return __uint_as_float(u);
}

#define RSBN 0.99999500003749977f  // 1/sqrt(1+1e-5)

// ---------- PREP: weights->bf16, relA2/relAT2 (fp16 c-pair packed), veA4 ----------
__global__ void k_prep(const float* __restrict__ base, const float* __restrict__ wq,
                       const float* __restrict__ w1, const float* __restrict__ w2,
                       short* __restrict__ wqb, short* __restrict__ w1b,
                       short* __restrict__ w2b, __half* __restrict__ relA2h,
                       __half* __restrict__ relAT2h, __half* __restrict__ veA4) {
  int blk = blockIdx.x;
  int tt = threadIdx.x;
  if (blk < 256) {             // weights
    int i = blk * 256 + tt;
    if (i < 32768) wqb[i] = f2b(wq[i]);
    w1b[i] = f2b(w1[i]);
    w2b[i] = f2b(w2[i]);
    return;
  }
  blk -= 256;
  if (blk < 265) {             // q_emb / k_emb^T, fp16 c-pair dword layout [cp][i][68]
    int idx = blk * 256 + tt;
    if (idx >= 16 * AA * AA) return;
    int j = idx % AA;
    int r = idx / AA;
    int i = r % AA;
    int c = r / AA;
    int ia, ib, ja, jb; float fi, fj;
    rz_taps(i, 255.0f / 65.0f, 255, ia, ib, fi);
    rz_taps(j, 255.0f / 65.0f, 255, ja, jb, fj);
    const float* S = base + (size_t)c * 255 * 255;
    float v = (1.0f - fi) * ((1.0f - fj) * S[ia * 255 + ja] + fj * S[ia * 255 + jb])
            + fi * ((1.0f - fj) * S[ib * 255 + ja] + fj * S[ib * 255 + jb]);
    if (c < 8) {
      relA2h[((((c >> 1) * 4420) + i * 68 + j) << 1) + (c & 1)] = __float2half(v);
    } else {
      int c2 = c - 8;
      relAT2h[((((c2 >> 1) * 4420) + j * 68 + i) << 1) + (c2 & 1)] = __float2half(v);
    }
    return;
  }
  blk -= 265;
  {  // veA4[c][ap4][i] float4-groups (8 halves = 8 a's); wave-coalesced AND x4-vector
    int idx = blk * 256 + tt;  // 16*72*128 = 147,456
    if (idx >= 16 * 72 * 128) return;
    int i = idx & 127;
    int r = idx >> 7;
    int a = r % 72, c = r / 72;
    float v = 0.f;
    if (a < 65) {
      int ia, ib; float fi;
      rz_taps(i, 65.0f / 128.0f, 65, ia, ib, fi);
      int ja, jb; float fj;
      rz_taps(a, 255.0f / 65.0f, 255, ja, jb, fj);
      int p0a, p0b; float g0;
      rz_taps(ia, 255.0f / 65.0f, 255, p0a, p0b, g0);
      int p1a, p1b; float g1;
      rz_taps(ib, 255.0f / 65.0f, 255, p1a, p1b, g1);
      const float* S = base + (size_t)(16 + c) * 255 * 255;
      float r0 = (1.0f - g0) * ((1.0f - fj) * S[p0a * 255 + ja] + fj * S[p0a * 255 + jb])
               + g0 * ((1.0f - fj) * S[p0b * 255 + ja] + fj * S[p0b * 255 + jb]);
      float r1 = (1.0f - g1) * ((1.0f - fj) * S[p1a * 255 + ja] + fj * S[p1a * 255 + jb])
               + g1 * ((1.0f - fj) * S[p1b * 255 + ja] + fj * S[p1b * 255 + jb]);
      v = (1.0f - fi) * r0 + fi * r1;
    }
    veA4[(((size_t)(c * 9 + (a >> 3)) * 128 + i) << 3) + (a & 7)] = __float2half(v);
  }
}

// ---------- MFMA GEMM 1: qkvT[n][g][w][a][oc32] = bf16(BN(Wqkv . downsample_i(x))) ----------
// Epilogue transposes via LDS so each lane writes one full 64B line per store.
__global__ __launch_bounds__(256) void k_qkv_mfma(
    const float* __restrict__ x, const short* __restrict__ wqb,
    const float* __restrict__ bg, const float* __restrict__ bb,
    short* __restrict__ out) {
  const int ob = blockIdx.x * 128;
  const int ya = blockIdx.y;           // a*2 + p-half
  const int a = ya >> 1;
  const int pb = (ya & 1) * 64;
  const int n = blockIdx.z;
  __shared__ short Asm[128 * 40];
  __shared__ short Bsm[64 * 40];
  __shared__ short Ct[128 * 65];       // 16,640 B transposed C stage
  const int t = threadIdx.x;
  const int lane = t & 63, wv = t >> 6;
  const int wm = wv >> 1, wn = wv & 1;
  const int lr = lane & 15, lk = (lane >> 4) * 8;
  int ia, ib; float f;
  rz_taps(a, 128.0f / 65.0f, 128, ia, ib, f);
  const float f0 = 1.0f - f;
  f32x4 acc[4][2];
  #pragma unroll
  for (int i = 0; i < 4; ++i)
    #pragma unroll
    for (int j = 0; j < 2; ++j)
      #pragma unroll
      for (int q = 0; q < 4; ++q) acc[i][j][q] = 0.f;
  const float* X = x + (size_t)n * 128 * 16384;
  for (int k0 = 0; k0 < 128; k0 += 32) {
    #pragma unroll
    for (int i2 = 0; i2 < 2; ++i2) {
      int u = t + 256 * i2;
      int row = u >> 2, kq = (u & 3) * 8;
      *(bf16x8*)&Asm[row * 40 + kq] = *(const bf16x8*)&wqb[(ob + row) * 128 + k0 + kq];
    }
    {
      int k = t >> 3, p8 = (t & 7) * 8;
      int c = k0 + k;
      const float* rowA = X + ((size_t)c * 128 + ia) * 128 + pb + p8;
      const float* rowB = X + ((size_t)c * 128 + ib) * 128 + pb + p8;
      float4 a0 = *(const float4*)rowA;
      float4 a1 = *(const float4*)(rowA + 4);
      float4 b0 = *(const float4*)rowB;
      float4 b1 = *(const float4*)(rowB + 4);
      short* d = &Bsm[p8 * 40 + k];
      d[0 * 40] = f2b(f0 * a0.x + f * b0.x);
      d[1 * 40] = f2b(f0 * a0.y + f * b0.y);
      d[2 * 40] = f2b(f0 * a0.z + f * b0.z);
      d[3 * 40] = f2b(f0 * a0.w + f * b0.w);
      d[4 * 40] = f2b(f0 * a1.x + f * b1.x);
      d[5 * 40] = f2b(f0 * a1.y + f * b1.y);
      d[6 * 40] = f2b(f0 * a1.z + f * b1.z);
      d[7 * 40] = f2b(f0 * a1.w + f * b1.w);
    }
    __syncthreads();
    bf16x8 af[4], bfr[2];
    #pragma unroll
    for (int mf = 0; mf < 4; ++mf) af[mf] = *(bf16x8*)&Asm[(wm * 64 + mf * 16 + lr) * 40 + lk];
    #pragma unroll
    for (int nf = 0; nf < 2; ++nf) bfr[nf] = *(bf16x8*)&Bsm[(wn * 32 + nf * 16 + lr) * 40 + lk];
    #pragma unroll
    for (int mf = 0; mf < 4; ++mf)
      #pragma unroll
      for (int nf = 0; nf < 2; ++nf)
        acc[mf][nf] = MFMA16(af[mf], bfr[nf], acc[mf][nf]);
    __syncthreads();
  }
  // stage BN'd C tile to LDS [128 o-local][65-pad w]
  #pragma unroll
  for (int mf = 0; mf < 4; ++mf) {
    #pragma unroll
    for (int r = 0; r < 4; ++r) {
      int ol = wm * 64 + mf * 16 + (lane >> 4) * 4 + r;
      int o = ob + ol;
      float sc = bg[o] * RSBN, sh = bb[o];
      #pragma unroll
      for (int nf = 0; nf < 2; ++nf) {
        int wl = wn * 32 + nf * 16 + lr;
        Ct[ol * 65 + wl] = f2b(acc[mf][nf][r] * sc + sh);
      }
    }
  }
  __syncthreads();
  // transposed store: wave wv handles gi=wv; lane = wl; 32 oc contiguous = 64B/lane
  {
    int gi = wv, wl = lane;
    int g = (ob >> 5) + gi;
    short* dst = out + (((size_t)((n * 8 + g) * 128) + pb + wl) * 65 + a) * 32;
    #pragma unroll
    for (int h8 = 0; h8 < 4; ++h8) {
      bf16x8 vv;
      #pragma unroll
      for (int e = 0; e < 8; ++e) vv[e] = Ct[(gi * 32 + h8 * 8 + e) * 65 + wl];
      *(bf16x8*)(dst + h8 * 8) = vv;
    }
  }
}

// ---------- F: fused sim(fp16 dot2) + softmax + x4-dot2 sv/sve + bn_out ----------
// q/k/v staging is one contiguous 4,160B coalesced load (qkvT layout).
__global__ void k_attn(const short* __restrict__ qkvT, const __half* __restrict__ relA2,
                       const __half* __restrict__ relAT2, const __half* __restrict__ veA4,
                       const float* __restrict__ sg, const float* __restrict__ sb,
                       const float* __restrict__ og, const float* __restrict__ ob,
                       float* __restrict__ yT) {
  int orig = blockIdx.x;
  int bg = ((orig & 7) << 8) + (orig >> 3);  // bijective XCD-chunk swizzle
  int b = bg >> 3, g = bg & 7;
  int n = b >> 7, w = b & 127;
  __shared__ __attribute__((aligned(16))) float Ss[65 * 68];   // 17,680 B; PwsH+Pinv after
  __shared__ __attribute__((aligned(16))) float qkbuf[536];    // 2,144 B: qs2|ks2
  __shared__ __attribute__((aligned(16))) __half vasH[16 * 72]; // 2,304 B
  __half* PwsH = (__half*)Ss;            // 128*66 halves = 16,896 B
  float* Pinv2 = Ss + 4224;              // floats 4224..4351 (beyond PwsH, within Ss)
  hf2* qs2 = (hf2*)qkbuf;
  hf2* ks2v = (hf2*)(qkbuf + 260);
  float* ks2f = qkbuf + 260;
  int t = threadIdx.x;
  const short* Qb = qkvT + (size_t)((n * 8 + g) * 128 + w) * 2080;  // 65a x 32oc

  // phase 1: coalesced raw load + in-register repack (q->qs2, k->ks2v, v->vasH)
  for (int l = t; l < 260; l += 256) {
    bf16x8 raw = *(const bf16x8*)(Qb + l * 8);
    int a = l >> 2;
    int seg = l & 3;   // 0:q(oc0-7) 1:k(oc8-15) 2:v c0-7 3:v c8-15
    if (seg == 0) {
      #pragma unroll
      for (int cp = 0; cp < 4; ++cp) {
        hf2 h;
        h[0] = (_Float16)b2f(raw[2 * cp]);
        h[1] = (_Float16)b2f(raw[2 * cp + 1]);
        qs2[cp * 65 + a] = h;
      }
    } else if (seg == 1) {
      #pragma unroll
      for (int cp = 0; cp < 4; ++cp) {
        hf2 h;
        h[0] = (_Float16)b2f(raw[2 * cp]);
        h[1] = (_Float16)b2f(raw[2 * cp + 1]);
        ks2v[cp * 68 + a] = h;
      }
    } else {
      int c0 = (seg - 2) * 8;
      #pragma unroll
      for (int e = 0; e < 8; ++e)
        vasH[(c0 + e) * 72 + a] = __float2half(b2f(raw[e]));
    }
  }
  if (t < 112) {   // zero vasH padding a=65..71
    int c = t / 7, ap = 65 + t % 7;
    vasH[c * 72 + ap] = __float2half(0.f);
  }
  __syncthreads();

  // phase 2: sim 65x65 via packed fdot2 (qk+qr+kr, BN-combined)
  {
    float sqk = sg[g] * RSBN, sqr = sg[8 + g] * RSBN, skr = sg[16 + g] * RSBN;
    float badd = sb[g] + sb[8 + g] + sb[16 + g];
    const float* rAf = (const float*)relA2;
    const float* rTf = (const float*)relAT2;
    const hf2* rAv = (const hf2*)relA2;
    const hf2* rTv = (const hf2*)relAT2;
    for (int u = t; u < 65 * 17; u += 256) {
      int i = u / 17, jq = u - i * 17;
      hf2 q2[4];
      #pragma unroll
      for (int cp = 0; cp < 4; ++cp) q2[cp] = qs2[cp * 65 + i];
      if (jq < 16) {
        int j0 = jq * 4;
        int lofs = i * 68 + j0;
        float qk0 = 0, qk1 = 0, qk2 = 0, qk3 = 0;
        float qr0 = 0, qr1 = 0, qr2 = 0, qr3 = 0;
        float kr0 = 0, kr1 = 0, kr2 = 0, kr3 = 0;
        #pragma unroll
        for (int cp = 0; cp < 4; ++cp) {
          float4 kq = *(const float4*)&ks2f[cp * 68 + j0];
          float4 ra = *(const float4*)&rAf[cp * 4420 + lofs];
          float4 rt = *(const float4*)&rTf[cp * 4420 + lofs];
          hf2 k0 = __builtin_bit_cast(hf2, kq.x);
          hf2 k1 = __builtin_bit_cast(hf2, kq.y);
          hf2 k2h = __builtin_bit_cast(hf2, kq.z);
          hf2 k3 = __builtin_bit_cast(hf2, kq.w);
          qk0 = FDOT2(k0, q2[cp], qk0);
          qk1 = FDOT2(k1, q2[cp], qk1);
          qk2 = FDOT2(k2h, q2[cp], qk2);
          qk3 = FDOT2(k3, q2[cp], qk3);
          qr0 = FDOT2(__builtin_bit_cast(hf2, ra.x), q2[cp], qr0);
          qr1 = FDOT2(__builtin_bit_cast(hf2, ra.y), q2[cp], qr1);
          qr2 = FDOT2(__builtin_bit_cast(hf2, ra.z), q2[cp], qr2);
          qr3 = FDOT2(__builtin_bit_cast(hf2, ra.w), q2[cp], qr3);
          kr0 = FDOT2(__builtin_bit_cast(hf2, rt.x), k0, kr0);
          kr1 = FDOT2(__builtin_bit_cast(hf2, rt.y), k1, kr1);
          kr2 = FDOT2(__builtin_bit_cast(hf2, rt.z), k2h, kr2);
          kr3 = FDOT2(__builtin_bit_cast(hf2, rt.w), k3, kr3);
        }
        float4 res;
        res.x = sqk * qk0 + sqr * qr0 + skr * kr0 + badd;
        res.y = sqk * qk1 + sqr * qr1 + skr * kr1 + badd;
        res.z = sqk * qk2 + sqr * qr2 + skr * kr2 + badd;
        res.w = sqk * qk3 + sqr * qr3 + skr * kr3 + badd;
        *(float4*)&Ss[lofs] = res;
      } else {
        int lofs = i * 68 + 64;
        float qk = 0, qr = 0, kr = 0;
        #pragma unroll
        for (int cp = 0; cp < 4; ++cp) {
          hf2 kv = ks2v[cp * 68 + 64];
          qk = FDOT2(kv, q2[cp], qk);
          qr = FDOT2(rAv[cp * 4420 + lofs], q2[cp], qr);
          kr = FDOT2(rTv[cp * 4420 + lofs], kv, kr);
        }
        Ss[lofs] = sqk * qk + sqr * qr + skr * kr + badd;
      }
    }
  }
  __syncthreads();

  // phase 3: register-T softmax fold (Pw/Pinv overwrite Ss after internal barrier)
  {
    const int i = t >> 1, h = t & 1;
    int ia, ib; float fi;
    rz_taps(i, 65.0f / 128.0f, 65, ia, ib, fi);
    const float* r0 = Ss + ia * 68 + h * 32;
    const float* r1 = Ss + ib * 68 + h * 32;
    const float wi0 = 1.0f - fi;
    float T[33];
    #pragma unroll
    for (int k4 = 0; k4 < 8; ++k4) {
      float4 a4 = *(const float4*)(r0 + 4 * k4);
      float4 b4 = *(const float4*)(r1 + 4 * k4);
      T[4 * k4 + 0] = wi0 * a4.x + fi * b4.x;
      T[4 * k4 + 1] = wi0 * a4.y + fi * b4.y;
      T[4 * k4 + 2] = wi0 * a4.z + fi * b4.z;
      T[4 * k4 + 3] = wi0 * a4.w + fi * b4.w;
    }
    T[32] = wi0 * r0[32] + fi * r1[32];
    float mx = T[0];
    #pragma unroll
    for (int k = 1; k < 33; ++k) mx = fmaxf(mx, T[k]);
    mx = fmaxf(mx, __shfl_xor(mx, 1));
    float p[33];
    #pragma unroll
    for (int k = 0; k < 33; ++k) p[k] = 0.f;
    float sum = 0.f;
    if (h == 0) {
      #pragma unroll
      for (int j = 0; j < 64; ++j) {
        JTAP(j, ja, jb, fj);
        float v = (1.0f - fj) * T[ja] + fj * T[jb];
        float e = __expf(v - mx);
        sum += e;
        p[ja] += e * (1.0f - fj);
        p[jb] += e * fj;
      }
    } else {
      #pragma unroll
      for (int j = 64; j < 128; ++j) {
        JTAP(j, ja, jb, fj);
        float v = (1.0f - fj) * T[ja - 32] + fj * T[jb - 32];
        float e = __expf(v - mx);
        sum += e;
        p[ja - 32] += e * (1.0f - fj);
        p[jb - 32] += e * fj;
      }
    }
    sum += __shfl_xor(sum, 1);
    float other = __shfl_xor(h ? p[0] : p[32], 1);
    __syncthreads();   // all Ss reads complete before Pw/Pinv overwrite the same LDS
    __half* prow = &PwsH[i * 66];
    if (h == 0) {
      p[32] += other;
      #pragma unroll
      for (int k = 0; k < 33; ++k) prow[k] = __float2half(p[k]);
      Pinv2[i] = 1.0f / sum;
    } else {
      p[0] += other;
      #pragma unroll
      for (int k = 0; k < 33; ++k) prow[32 + k] = __float2half(p[k]);
      prow[65] = __float2half(0.f);
    }
  }
  __syncthreads();

  // phase 4: x4-vectorized dot2 (float4 LDS vas + float4 coalesced veA4)
  {
    const int i = t & 127;
    const int cg = t >> 7;
    const float inv = Pinv2[i];
    hf2 pw[33];
    const hf2* prow2 = (const hf2*)&PwsH[i * 66];
    #pragma unroll
    for (int ap = 0; ap < 33; ++ap) pw[ap] = prow2[ap];
    #pragma unroll
    for (int l = 0; l < 8; ++l) {
      const int c = cg * 8 + l;
      const float4* vr4 = (const float4*)&vasH[c * 72];
      const float4* vp4 = (const float4*)veA4 + (size_t)(c * 9) * 128 + i;
      float sv0 = 0.f, sv1 = 0.f, se0 = 0.f, se1 = 0.f;
      #pragma unroll
      for (int q4 = 0; q4 < 8; ++q4) {
        float4 a4 = vr4[q4];
        float4 b4 = vp4[(size_t)q4 * 128];
        sv0 = FDOT2(__builtin_bit_cast(hf2, a4.x), pw[4 * q4 + 0], sv0);
        sv1 = FDOT2(__builtin_bit_cast(hf2, a4.y), pw[4 * q4 + 1], sv1);
        sv0 = FDOT2(__builtin_bit_cast(hf2, a4.z), pw[4 * q4 + 2], sv0);
        sv1 = FDOT2(__builtin_bit_cast(hf2, a4.w), pw[4 * q4 + 3], sv1);
        se0 = FDOT2(__builtin_bit_cast(hf2, b4.x), pw[4 * q4 + 0], se0);
        se1 = FDOT2(__builtin_bit_cast(hf2, b4.y), pw[4 * q4 + 1], se1);
        se0 = FDOT2(__builtin_bit_cast(hf2, b4.z), pw[4 * q4 + 2], se0);
        se1 = FDOT2(__builtin_bit_cast(hf2, b4.w), pw[4 * q4 + 3], se1);
      }
      {  // tail: ap=32
        float4 a4 = vr4[8];
        float4 b4 = vp4[(size_t)8 * 128];
        sv0 = FDOT2(__builtin_bit_cast(hf2, a4.x), pw[32], sv0);
        se0 = FDOT2(__builtin_bit_cast(hf2, b4.x), pw[32], se0);
      }
      float sv = sv0 + sv1, se = se0 + se1;
      int c2 = g * 16 + c;
      int o0 = 2 * c2;
      float val = og[o0] * RSBN * (sv * inv) + ob[o0]
                + og[o0 + 1] * RSBN * (se * inv) + ob[o0 + 1];
      yT[((size_t)(n * 128 + c2)) * 16384 + w * 128 + i] = val;
    }
  }
}

// ---------- XS: stage yT plane (fp32 LDS), emit xnb (shift+IN, bf16) + yStd (fp32) ----------
__global__ __launch_bounds__(256) void k_xs(const float* __restrict__ yT,
                                            const float* __restrict__ inw,
                                            const float* __restrict__ inb,
                                            short* __restrict__ xnb,
                                            float* __restrict__ yStd) {
  int gid = blockIdx.x;
  int n, cs, cx = -1;
  bool wStd;
  if (gid < 256) {
    n = gid >> 7; cx = gid & 127;
    cs = (cx < 40) ? (cx % 10) : cx;
    wStd = (cx < 10) || (cx >= 40);
  } else {
    int u = gid - 256;
    n = u / 30; cs = 10 + (u % 30);
    wStd = true;
  }
  int dh = 0, dw = 0;
  if (cx >= 0) {
    if (cx < 10)       dw = -2;
    else if (cx < 20)  dw = 2;
    else if (cx < 30)  dh = -2;
    else if (cx < 40)  dh = 2;
  }
  __shared__ float Sb[128 * 130];
  __shared__ float sm[8];
  const float* src = yT + ((size_t)(n * 128 + cs)) * 16384;
  int t = threadIdx.x;
  #pragma unroll
  for (int l = 0; l < 16; ++l) {
    int q = t + l * 256;
    float4 v = *(const float4*)&src[q * 4];
    int w = q >> 5, i0 = (q * 4) & 127;
    float* d = &Sb[w * 130 + i0];
    *(float2*)d = make_float2(v.x, v.y);
    *(float2*)(d + 2) = make_float2(v.z, v.w);
  }
  __syncthreads();
  if (wStd) {
    float* dst = yStd + ((size_t)(n * 128 + cs)) * 16384;
    for (int l = 0; l < 64; ++l) {
      int idx = t + l * 256;
      int h = idx >> 7, w = idx & 127;
      dst[idx] = Sb[w * 130 + h];
    }
  }
  if (cx >= 0) {
    float s = 0.f, q2 = 0.f;
    for (int l = 0; l < 64; ++l) {
      int idx = t + l * 256;
      int h = idx >> 7, w = idx & 127;
      int hs = h + dh, ws = w + dw;
      float v = (hs >= 0 && hs < 128 && ws >= 0 && ws < 128) ? Sb[ws * 130 + hs] : 0.f;
      s += v; q2 += v * v;
    }
    #pragma unroll
    for (int o = 32; o; o >>= 1) { s += __shfl_down(s, o); q2 += __shfl_down(q2, o); }
    if ((t & 63) == 0) { sm[(t >> 6) * 2] = s; sm[(t >> 6) * 2 + 1] = q2; }
    __syncthreads();
    float S_ = sm[0] + sm[2] + sm[4] + sm[6];
    float Q_ = sm[1] + sm[3] + sm[5] + sm[7];
    float mean = S_ * (1.0f / 16384.0f);
    float var = Q_ * (1.0f / 16384.0f) - mean * mean;
    float scale = inw[cx] * rsqrtf(var + 1e-5f);
    float shift = inb[cx] - mean * scale;
    short* dst = xnb + ((size_t)(n * 128 + cx)) * 16384;
    for (int l = 0; l < 64; ++l) {
      int idx = t + l * 256;
      int h = idx >> 7, w = idx & 127;
      int hs = h + dh, ws = w + dw;
      float v = (hs >= 0 && hs < 128 && ws >= 0 && ws < 128) ? Sb[ws * 130 + hs] : 0.f;
      dst[idx] = f2b(v * scale + shift);
    }
  }
}

// ---------- FUSED MLP: out = W2 . gelu(W1 . xn) + yStd; 32-pixel tiles ----------
__global__ __launch_bounds__(256) void k_mlp(
    const short* __restrict__ xnb, const short* __restrict__ w1b,
    const short* __restrict__ w2b, const float* __restrict__ y,
    float* __restrict__ out) {
  const int pb = blockIdx.x * 32;
  const int n = blockIdx.z;
  __shared__ short Asm[128 * 40];
  __shared__ short Bxn[32 * 136];
  __shared__ short h1s[32 * 136];
  const int t = threadIdx.x;
  const int lane = t & 63, wv = t >> 6;
  const int wm = wv >> 1, wn = wv & 1;
  const int lr = lane & 15, lk = (lane >> 4) * 8;
  const short* X = xnb + (size_t)n * 128 * 16384;
  #pragma unroll
  for (int i2 = 0; i2 < 2; ++i2) {
    int u = t + 256 * i2;
    int c = u >> 2, p0 = (u & 3) * 8;
    bf16x8 hv = *(const bf16x8*)&X[(size_t)c * 16384 + pb + p0];
    #pragma unroll
    for (int j = 0; j < 8; ++j) Bxn[(p0 + j) * 136 + c] = hv[j];
  }
  f32x4 acc2[4][1];
  #pragma unroll
  for (int i = 0; i < 4; ++i)
    #pragma unroll
    for (int q = 0; q < 4; ++q) acc2[i][0][q] = 0.f;
  __syncthreads();

  for (int och = 0; och < 4; ++och) {
    f32x4 acc1[4][1];
    #pragma unroll
    for (int i = 0; i < 4; ++i)
      #pragma unroll
      for (int q = 0; q < 4; ++q) acc1[i][0][q] = 0.f;
    for (int c0 = 0; c0 < 128; c0 += 32) {
      #pragma unroll
      for (int i2 = 0; i2 < 2; ++i2) {
        int u = t + 256 * i2;
        int row = u >> 2, kq = (u & 3) * 8;
        *(bf16x8*)&Asm[row * 40 + kq] =
            *(const bf16x8*)&w1b[(och * 128 + row) * 128 + c0 + kq];
      }
      __syncthreads();
      bf16x8 af[4], bfr;
      #pragma unroll
      for (int mf = 0; mf < 4; ++mf)
        af[mf] = *(bf16x8*)&Asm[(wm * 64 + mf * 16 + lr) * 40 + lk];
      bfr = *(bf16x8*)&Bxn[(wn * 16 + lr) * 136 + c0 + lk];
      #pragma unroll
      for (int mf = 0; mf < 4; ++mf)
        acc1[mf][0] = MFMA16(af[mf], bfr, acc1[mf][0]);
      __syncthreads();
    }
    #pragma unroll
    for (int mf = 0; mf < 4; ++mf)
      #pragma unroll
      for (int r = 0; r < 4; ++r) {
        int o = wm * 64 + mf * 16 + (lane >> 4) * 4 + r;
        int p = wn * 16 + lr;
        h1s[p * 136 + o] = f2b(gelu_exact(acc1[mf][0][r]));
      }
    for (int k0 = 0; k0 < 128; k0 += 32) {
      #pragma unroll
      for (int i2 = 0; i2 < 2; ++i2) {
        int u = t + 256 * i2;
        int row = u >> 2, kq = (u & 3) * 8;
        *(bf16x8*)&Asm[row * 40 + kq] =
            *(const bf16x8*)&w2b[row * 512 + och * 128 + k0 + kq];
      }
      __syncthreads();
      bf16x8 af[4], bfr;
      #pragma unroll
      for (int mf = 0; mf < 4; ++mf)
        af[mf] = *(bf16x8*)&Asm[(wm * 64 + mf * 16 + lr) * 40 + lk];
      bfr = *(bf16x8*)&h1s[(wn * 16 + lr) * 136 + k0 + lk];
      #pragma unroll
      for (int mf = 0; mf < 4; ++mf)
        acc2[mf][0] = MFMA16(af[mf], bfr, acc2[mf][0]);
      __syncthreads();
    }
  }
  #pragma unroll
  for (int mf = 0; mf < 4; ++mf)
    #pragma unroll
    for (int r = 0; r < 4; ++r) {
      int o = wm * 64 + mf * 16 + (lane >> 4) * 4 + r;
      int p = pb + wn * 16 + lr;
      size_t base = ((size_t)(n * 128 + o)) * 16384 + p;
      out[base] = acc2[mf][0][r] + y[base];
    }
}

extern "C" void kernel_launch(void* const* d_in, const int* in_sizes, int n_in,
                              void* d_out, int out_size, void* d_ws, size_t ws_size,
                              hipStream_t stream) {
  const float* x        = (const float*)d_in[0];
  const float* w_qkv    = (const float*)d_in[1];
  const float* bn_qkv_g = (const float*)d_in[2];
  const float* bn_qkv_b = (const float*)d_in[3];
  const float* bn_sim_g = (const float*)d_in[4];
  const float* bn_sim_b = (const float*)d_in[5];
  const float* bn_out_g = (const float*)d_in[6];
  const float* bn_out_b = (const float*)d_in[7];
  const float* in_w     = (const float*)d_in[8];
  const float* in_b     = (const float*)d_in[9];
  const float* mlp_w1   = (const float*)d_in[10];
  const float* mlp_w2   = (const float*)d_in[11];
  const float* base_rel = (const float*)d_in[12];
  float* Wp = (float*)d_ws;

  __half* relA2  = (__half*)(Wp + 0);        // 17,680 f
  __half* relAT2 = (__half*)(Wp + 17680);    // 17,680 f
  __half* veA4   = (__half*)(Wp + 35360);    // 147,456 halves = 73,728 f
  float* yT      = Wp + 109088;              // 4,194,304
  float* yStd    = Wp + 4303392;             // 4,194,304
  short* wqb     = (short*)(Wp + 8497696);   // 32,768 shorts
  short* w1b     = (short*)(Wp + 8514080);   // 65,536 shorts
  short* w2b     = (short*)(Wp + 8546848);   // 65,536 shorts
  short* xnb     = (short*)(Wp + 8579616);   // 4,194,304 shorts
  short* qkvT    = (short*)(Wp + 10676768);  // 4,259,840 shorts
  // peak: 12,806,688 floats = 51.2 MB

  k_prep<<<dim3(1097), dim3(256), 0, stream>>>(base_rel, w_qkv, mlp_w1, mlp_w2,
                                               wqb, w1b, w2b, relA2, relAT2, veA4);
  k_qkv_mfma<<<dim3(2, 130, 2), dim3(256), 0, stream>>>(x, wqb, bn_qkv_g, bn_qkv_b, qkvT);
  k_attn<<<dim3(2048), dim3(256), 0, stream>>>(qkvT, relA2, relAT2, veA4,
                                               bn_sim_g, bn_sim_b, bn_out_g, bn_out_b, yT);
  k_xs<<<dim3(316), dim3(256), 0, stream>>>(yT, in_w, in_b, xnb, yStd);
  k_mlp<<<dim3(512, 1, 2), dim3(256), 0, stream>>>(xnb, w1b, w2b, yStd, (float*)d_out);
}

// Round 20
// 114.125 us; speedup vs baseline: 1.0769x; 1.0037x over previous
//
#include <hip/hip_runtime.h>
#include <hip/hip_bf16.h>
#include <hip/hip_fp16.h>

#define GG 8
#define AA 65
#define BB 256

typedef __attribute__((ext_vector_type(8))) short bf16x8;
typedef __attribute__((ext_vector_type(4))) short s16x4;
typedef __attribute__((ext_vector_type(4))) float f32x4;
typedef _Float16 hf2 __attribute__((ext_vector_type(2)));
#define MFMA16(a, b, c) __builtin_amdgcn_mfma_f32_16x16x32_bf16(a, b, c, 0, 0, 0)
#define FDOT2(a, b, c) __builtin_amdgcn_fdot2((a), (b), (c), false)

__device__ __forceinline__ void rz_taps(int o, float scale, int in_size,
                                        int& ia, int& ib, float& f) {
  float pos = (o + 0.5f) * scale - 0.5f;
  float fl = floorf(pos);
  int i0 = (int)fl;
  f = pos - fl;
  ia = i0 < 0 ? 0 : i0;
  int i1 = i0 + 1;
  ib = i1 > (in_size - 1) ? (in_size - 1) : i1;
}

// Compile-time 128->65 tap: pos = (j+0.5)*65/128-0.5 = (130j-63)/256 exactly.
#define JTAP(jc, ja, jb, fj) \
  const int num_ = 130 * (jc) - 63;               \
  const int fl_ = num_ >> 8;                      \
  const int ja = fl_ < 0 ? 0 : fl_;               \
  const int jb = (fl_ + 1 > 64) ? 64 : (fl_ + 1); \
  const float fj = (float)(num_ - (fl_ << 8)) * 0.00390625f;

__device__ __forceinline__ float gelu_exact(float v) {
  return 0.5f * v * (1.0f + erff(v * 0.70710678118654752f));
}

__device__ __forceinline__ short f2b(float f) {
  __hip_bfloat16 h = __float2bfloat16(f);
  return *reinterpret_cast<short*>(&h);
}
__device__ __forceinline__ float b2f(short s) {
  unsigned int u = ((unsigned int)(unsigned short)s) << 16;
  return __uint_as_float(u);
}

#define RSBN 0.99999500003749977f  // 1/sqrt(1+1e-5)

// ---------- PREP: weights->bf16, relA2/relAT2 (fp16 c-pair packed), veA4 ----------
__global__ void k_prep(const float* __restrict__ base, const float* __restrict__ wq,
                       const float* __restrict__ w1, const float* __restrict__ w2,
                       short* __restrict__ wqb, short* __restrict__ w1b,
                       short* __restrict__ w2b, __half* __restrict__ relA2h,
                       __half* __restrict__ relAT2h, __half* __restrict__ veA4) {
  int blk = blockIdx.x;
  int tt = threadIdx.x;
  if (blk < 256) {             // weights
    int i = blk * 256 + tt;
    if (i < 32768) wqb[i] = f2b(wq[i]);
    w1b[i] = f2b(w1[i]);
    w2b[i] = f2b(w2[i]);
    return;
  }
  blk -= 256;
  if (blk < 265) {             // q_emb / k_emb^T, fp16 c-pair dword layout [cp][i][68]
    int idx = blk * 256 + tt;
    if (idx >= 16 * AA * AA) return;
    int j = idx % AA;
    int r = idx / AA;
    int i = r % AA;
    int c = r / AA;
    int ia, ib, ja, jb; float fi, fj;
    rz_taps(i, 255.0f / 65.0f, 255, ia, ib, fi);
    rz_taps(j, 255.0f / 65.0f, 255, ja, jb, fj);
    const float* S = base + (size_t)c * 255 * 255;
    float v = (1.0f - fi) * ((1.0f - fj) * S[ia * 255 + ja] + fj * S[ia * 255 + jb])
            + fi * ((1.0f - fj) * S[ib * 255 + ja] + fj * S[ib * 255 + jb]);
    if (c < 8) {
      relA2h[((((c >> 1) * 4420) + i * 68 + j) << 1) + (c & 1)] = __float2half(v);
    } else {
      int c2 = c - 8;
      relAT2h[((((c2 >> 1) * 4420) + j * 68 + i) << 1) + (c2 & 1)] = __float2half(v);
    }
    return;
  }
  blk -= 265;
  {  // veA4[c][ap4][i] float4-groups (8 halves = 8 a's); wave-coalesced AND x4-vector
    int idx = blk * 256 + tt;  // 16*72*128 = 147,456
    if (idx >= 16 * 72 * 128) return;
    int i = idx & 127;
    int r = idx >> 7;
    int a = r % 72, c = r / 72;
    float v = 0.f;
    if (a < 65) {
      int ia, ib; float fi;
      rz_taps(i, 65.0f / 128.0f, 65, ia, ib, fi);
      int ja, jb; float fj;
      rz_taps(a, 255.0f / 65.0f, 255, ja, jb, fj);
      int p0a, p0b; float g0;
      rz_taps(ia, 255.0f / 65.0f, 255, p0a, p0b, g0);
      int p1a, p1b; float g1;
      rz_taps(ib, 255.0f / 65.0f, 255, p1a, p1b, g1);
      const float* S = base + (size_t)(16 + c) * 255 * 255;
      float r0 = (1.0f - g0) * ((1.0f - fj) * S[p0a * 255 + ja] + fj * S[p0a * 255 + jb])
               + g0 * ((1.0f - fj) * S[p0b * 255 + ja] + fj * S[p0b * 255 + jb]);
      float r1 = (1.0f - g1) * ((1.0f - fj) * S[p1a * 255 + ja] + fj * S[p1a * 255 + jb])
               + g1 * ((1.0f - fj) * S[p1b * 255 + ja] + fj * S[p1b * 255 + jb]);
      v = (1.0f - fi) * r0 + fi * r1;
    }
    veA4[(((size_t)(c * 9 + (a >> 3)) * 128 + i) << 3) + (a & 7)] = __float2half(v);
  }
}

// ---------- MFMA GEMM 1: qkvT[n][g][w][a][oc32] = bf16(BN(Wqkv . downsample_i(x))) ----------
__global__ __launch_bounds__(256) void k_qkv_mfma(
    const float* __restrict__ x, const short* __restrict__ wqb,
    const float* __restrict__ bg, const float* __restrict__ bb,
    short* __restrict__ out) {
  const int ob = blockIdx.x * 128;
  const int ya = blockIdx.y;           // a*2 + p-half
  const int a = ya >> 1;
  const int pb = (ya & 1) * 64;
  const int n = blockIdx.z;
  __shared__ short Asm[128 * 40];
  __shared__ short Bsm[64 * 40];
  __shared__ short Ct[128 * 65];       // 16,640 B transposed C stage
  const int t = threadIdx.x;
  const int lane = t & 63, wv = t >> 6;
  const int wm = wv >> 1, wn = wv & 1;
  const int lr = lane & 15, lk = (lane >> 4) * 8;
  int ia, ib; float f;
  rz_taps(a, 128.0f / 65.0f, 128, ia, ib, f);
  const float f0 = 1.0f - f;
  f32x4 acc[4][2];
  #pragma unroll
  for (int i = 0; i < 4; ++i)
    #pragma unroll
    for (int j = 0; j < 2; ++j)
      #pragma unroll
      for (int q = 0; q < 4; ++q) acc[i][j][q] = 0.f;
  const float* X = x + (size_t)n * 128 * 16384;
  for (int k0 = 0; k0 < 128; k0 += 32) {
    #pragma unroll
    for (int i2 = 0; i2 < 2; ++i2) {
      int u = t + 256 * i2;
      int row = u >> 2, kq = (u & 3) * 8;
      *(bf16x8*)&Asm[row * 40 + kq] = *(const bf16x8*)&wqb[(ob + row) * 128 + k0 + kq];
    }
    {
      int k = t >> 3, p8 = (t & 7) * 8;
      int c = k0 + k;
      const float* rowA = X + ((size_t)c * 128 + ia) * 128 + pb + p8;
      const float* rowB = X + ((size_t)c * 128 + ib) * 128 + pb + p8;
      float4 a0 = *(const float4*)rowA;
      float4 a1 = *(const float4*)(rowA + 4);
      float4 b0 = *(const float4*)rowB;
      float4 b1 = *(const float4*)(rowB + 4);
      short* d = &Bsm[p8 * 40 + k];
      d[0 * 40] = f2b(f0 * a0.x + f * b0.x);
      d[1 * 40] = f2b(f0 * a0.y + f * b0.y);
      d[2 * 40] = f2b(f0 * a0.z + f * b0.z);
      d[3 * 40] = f2b(f0 * a0.w + f * b0.w);
      d[4 * 40] = f2b(f0 * a1.x + f * b1.x);
      d[5 * 40] = f2b(f0 * a1.y + f * b1.y);
      d[6 * 40] = f2b(f0 * a1.z + f * b1.z);
      d[7 * 40] = f2b(f0 * a1.w + f * b1.w);
    }
    __syncthreads();
    bf16x8 af[4], bfr[2];
    #pragma unroll
    for (int mf = 0; mf < 4; ++mf) af[mf] = *(bf16x8*)&Asm[(wm * 64 + mf * 16 + lr) * 40 + lk];
    #pragma unroll
    for (int nf = 0; nf < 2; ++nf) bfr[nf] = *(bf16x8*)&Bsm[(wn * 32 + nf * 16 + lr) * 40 + lk];
    #pragma unroll
    for (int mf = 0; mf < 4; ++mf)
      #pragma unroll
      for (int nf = 0; nf < 2; ++nf)
        acc[mf][nf] = MFMA16(af[mf], bfr[nf], acc[mf][nf]);
    __syncthreads();
  }
  // stage BN'd C tile to LDS [128 o-local][65-pad w]
  #pragma unroll
  for (int mf = 0; mf < 4; ++mf) {
    #pragma unroll
    for (int r = 0; r < 4; ++r) {
      int ol = wm * 64 + mf * 16 + (lane >> 4) * 4 + r;
      int o = ob + ol;
      float sc = bg[o] * RSBN, sh = bb[o];
      #pragma unroll
      for (int nf = 0; nf < 2; ++nf) {
        int wl = wn * 32 + nf * 16 + lr;
        Ct[ol * 65 + wl] = f2b(acc[mf][nf][r] * sc + sh);
      }
    }
  }
  __syncthreads();
  // transposed store: wave wv handles gi=wv; lane = wl; 32 oc contiguous = 64B/lane
  {
    int gi = wv, wl = lane;
    int g = (ob >> 5) + gi;
    short* dst = out + (((size_t)((n * 8 + g) * 128) + pb + wl) * 65 + a) * 32;
    #pragma unroll
    for (int h8 = 0; h8 < 4; ++h8) {
      bf16x8 vv;
      #pragma unroll
      for (int e = 0; e < 8; ++e) vv[e] = Ct[(gi * 32 + h8 * 8 + e) * 65 + wl];
      *(bf16x8*)(dst + h8 * 8) = vv;
    }
  }
}

// ---------- F: fused sim(fp16 dot2) + softmax + x4-dot2 sv/sve + bn_out ----------
// Coalesced qkvT reads; v staged in phase 3 overlaying the dead q/k buffer ->
// LDS 19,984 B = 8 blocks/CU (single co-resident round).
__global__ void k_attn(const short* __restrict__ qkvT, const __half* __restrict__ relA2,
                       const __half* __restrict__ relAT2, const __half* __restrict__ veA4,
                       const float* __restrict__ sg, const float* __restrict__ sb,
                       const float* __restrict__ og, const float* __restrict__ ob,
                       float* __restrict__ yT) {
  int orig = blockIdx.x;
  int bg = ((orig & 7) << 8) + (orig >> 3);  // bijective XCD-chunk swizzle
  int b = bg >> 3, g = bg & 7;
  int n = b >> 7, w = b & 127;
  __shared__ __attribute__((aligned(16))) float Ss[65 * 68];   // 17,680 B; PwsH+Pinv after
  __shared__ __attribute__((aligned(16))) float u0[576];       // 2,304 B: qs2|ks2 -> vasH
  __half* PwsH = (__half*)Ss;            // 128*66 halves = 16,896 B
  float* Pinv2 = Ss + 4224;              // floats 4224..4351 (beyond PwsH, within Ss)
  hf2* qs2 = (hf2*)u0;
  hf2* ks2v = (hf2*)(u0 + 260);
  float* ks2f = u0 + 260;
  __half* vasH = (__half*)u0;            // phase-3/4 overlay (16*72 halves = 2,304 B)
  int t = threadIdx.x;
  const short* Qb = qkvT + (size_t)((n * 8 + g) * 128 + w) * 2080;  // 65a x 32oc

  // phase 1: coalesced q/k load + in-register repack (v deferred to phase 3)
  for (int l = t; l < 130; l += 256) {
    int a = l >> 1, seg = l & 1;       // 0:q(oc0-7) 1:k(oc8-15)
    bf16x8 raw = *(const bf16x8*)(Qb + (a * 4 + seg) * 8);
    if (seg == 0) {
      #pragma unroll
      for (int cp = 0; cp < 4; ++cp) {
        hf2 h;
        h[0] = (_Float16)b2f(raw[2 * cp]);
        h[1] = (_Float16)b2f(raw[2 * cp + 1]);
        qs2[cp * 65 + a] = h;
      }
    } else {
      #pragma unroll
      for (int cp = 0; cp < 4; ++cp) {
        hf2 h;
        h[0] = (_Float16)b2f(raw[2 * cp]);
        h[1] = (_Float16)b2f(raw[2 * cp + 1]);
        ks2v[cp * 68 + a] = h;
      }
    }
  }
  __syncthreads();

  // phase 2: sim 65x65 via packed fdot2 (qk+qr+kr, BN-combined)
  {
    float sqk = sg[g] * RSBN, sqr = sg[8 + g] * RSBN, skr = sg[16 + g] * RSBN;
    float badd = sb[g] + sb[8 + g] + sb[16 + g];
    const float* rAf = (const float*)relA2;
    const float* rTf = (const float*)relAT2;
    const hf2* rAv = (const hf2*)relA2;
    const hf2* rTv = (const hf2*)relAT2;
    for (int u = t; u < 65 * 17; u += 256) {
      int i = u / 17, jq = u - i * 17;
      hf2 q2[4];
      #pragma unroll
      for (int cp = 0; cp < 4; ++cp) q2[cp] = qs2[cp * 65 + i];
      if (jq < 16) {
        int j0 = jq * 4;
        int lofs = i * 68 + j0;
        float qk0 = 0, qk1 = 0, qk2 = 0, qk3 = 0;
        float qr0 = 0, qr1 = 0, qr2 = 0, qr3 = 0;
        float kr0 = 0, kr1 = 0, kr2 = 0, kr3 = 0;
        #pragma unroll
        for (int cp = 0; cp < 4; ++cp) {
          float4 kq = *(const float4*)&ks2f[cp * 68 + j0];
          float4 ra = *(const float4*)&rAf[cp * 4420 + lofs];
          float4 rt = *(const float4*)&rTf[cp * 4420 + lofs];
          hf2 k0 = __builtin_bit_cast(hf2, kq.x);
          hf2 k1 = __builtin_bit_cast(hf2, kq.y);
          hf2 k2h = __builtin_bit_cast(hf2, kq.z);
          hf2 k3 = __builtin_bit_cast(hf2, kq.w);
          qk0 = FDOT2(k0, q2[cp], qk0);
          qk1 = FDOT2(k1, q2[cp], qk1);
          qk2 = FDOT2(k2h, q2[cp], qk2);
          qk3 = FDOT2(k3, q2[cp], qk3);
          qr0 = FDOT2(__builtin_bit_cast(hf2, ra.x), q2[cp], qr0);
          qr1 = FDOT2(__builtin_bit_cast(hf2, ra.y), q2[cp], qr1);
          qr2 = FDOT2(__builtin_bit_cast(hf2, ra.z), q2[cp], qr2);
          qr3 = FDOT2(__builtin_bit_cast(hf2, ra.w), q2[cp], qr3);
          kr0 = FDOT2(__builtin_bit_cast(hf2, rt.x), k0, kr0);
          kr1 = FDOT2(__builtin_bit_cast(hf2, rt.y), k1, kr1);
          kr2 = FDOT2(__builtin_bit_cast(hf2, rt.z), k2h, kr2);
          kr3 = FDOT2(__builtin_bit_cast(hf2, rt.w), k3, kr3);
        }
        float4 res;
        res.x = sqk * qk0 + sqr * qr0 + skr * kr0 + badd;
        res.y = sqk * qk1 + sqr * qr1 + skr * kr1 + badd;
        res.z = sqk * qk2 + sqr * qr2 + skr * kr2 + badd;
        res.w = sqk * qk3 + sqr * qr3 + skr * kr3 + badd;
        *(float4*)&Ss[lofs] = res;
      } else {
        int lofs = i * 68 + 64;
        float qk = 0, qr = 0, kr = 0;
        #pragma unroll
        for (int cp = 0; cp < 4; ++cp) {
          hf2 kv = ks2v[cp * 68 + 64];
          qk = FDOT2(kv, q2[cp], qk);
          qr = FDOT2(rAv[cp * 4420 + lofs], q2[cp], qr);
          kr = FDOT2(rTv[cp * 4420 + lofs], kv, kr);
        }
        Ss[lofs] = sqk * qk + sqr * qr + skr * kr + badd;
      }
    }
  }
  __syncthreads();   // sim reads of q/k complete -> u0 reusable as vasH

  // phase 3: v stage (overlays u0; coalesced 32B-contiguous per a) + softmax fold
  for (int l = t; l < 130; l += 256) {
    int a = l >> 1, hi = l & 1;        // hi: v c0-7 / c8-15
    bf16x8 raw = *(const bf16x8*)(Qb + (a * 4 + 2 + hi) * 8);
    #pragma unroll
    for (int e = 0; e < 8; ++e)
      vasH[(hi * 8 + e) * 72 + a] = __float2half(b2f(raw[e]));
  }
  if (t < 112) {   // zero vasH padding a=65..71
    int c = t / 7, ap = 65 + t % 7;
    vasH[c * 72 + ap] = __float2half(0.f);
  }
  {
    const int i = t >> 1, h = t & 1;
    int ia, ib; float fi;
    rz_taps(i, 65.0f / 128.0f, 65, ia, ib, fi);
    const float* r0 = Ss + ia * 68 + h * 32;
    const float* r1 = Ss + ib * 68 + h * 32;
    const float wi0 = 1.0f - fi;
    float T[33];
    #pragma unroll
    for (int k4 = 0; k4 < 8; ++k4) {
      float4 a4 = *(const float4*)(r0 + 4 * k4);
      float4 b4 = *(const float4*)(r1 + 4 * k4);
      T[4 * k4 + 0] = wi0 * a4.x + fi * b4.x;
      T[4 * k4 + 1] = wi0 * a4.y + fi * b4.y;
      T[4 * k4 + 2] = wi0 * a4.z + fi * b4.z;
      T[4 * k4 + 3] = wi0 * a4.w + fi * b4.w;
    }
    T[32] = wi0 * r0[32] + fi * r1[32];
    float mx = T[0];
    #pragma unroll
    for (int k = 1; k < 33; ++k) mx = fmaxf(mx, T[k]);
    mx = fmaxf(mx, __shfl_xor(mx, 1));
    float p[33];
    #pragma unroll
    for (int k = 0; k < 33; ++k) p[k] = 0.f;
    float sum = 0.f;
    if (h == 0) {
      #pragma unroll
      for (int j = 0; j < 64; ++j) {
        JTAP(j, ja, jb, fj);
        float v = (1.0f - fj) * T[ja] + fj * T[jb];
        float e = __expf(v - mx);
        sum += e;
        p[ja] += e * (1.0f - fj);
        p[jb] += e * fj;
      }
    } else {
      #pragma unroll
      for (int j = 64; j < 128; ++j) {
        JTAP(j, ja, jb, fj);
        float v = (1.0f - fj) * T[ja - 32] + fj * T[jb - 32];
        float e = __expf(v - mx);
        sum += e;
        p[ja - 32] += e * (1.0f - fj);
        p[jb - 32] += e * fj;
      }
    }
    sum += __shfl_xor(sum, 1);
    float other = __shfl_xor(h ? p[0] : p[32], 1);
    __syncthreads();   // all Ss reads complete before Pw/Pinv overwrite the same LDS
    __half* prow = &PwsH[i * 66];
    if (h == 0) {
      p[32] += other;
      #pragma unroll
      for (int k = 0; k < 33; ++k) prow[k] = __float2half(p[k]);
      Pinv2[i] = 1.0f / sum;
    } else {
      p[0] += other;
      #pragma unroll
      for (int k = 0; k < 33; ++k) prow[32 + k] = __float2half(p[k]);
      prow[65] = __float2half(0.f);
    }
  }
  __syncthreads();

  // phase 4: x4-vectorized dot2 (float4 LDS vas + float4 coalesced veA4)
  {
    const int i = t & 127;
    const int cg = t >> 7;
    const float inv = Pinv2[i];
    hf2 pw[33];
    const hf2* prow2 = (const hf2*)&PwsH[i * 66];
    #pragma unroll
    for (int ap = 0; ap < 33; ++ap) pw[ap] = prow2[ap];
    #pragma unroll
    for (int l = 0; l < 8; ++l) {
      const int c = cg * 8 + l;
      const float4* vr4 = (const float4*)&vasH[c * 72];
      const float4* vp4 = (const float4*)veA4 + (size_t)(c * 9) * 128 + i;
      float sv0 = 0.f, sv1 = 0.f, se0 = 0.f, se1 = 0.f;
      #pragma unroll
      for (int q4 = 0; q4 < 8; ++q4) {
        float4 a4 = vr4[q4];
        float4 b4 = vp4[(size_t)q4 * 128];
        sv0 = FDOT2(__builtin_bit_cast(hf2, a4.x), pw[4 * q4 + 0], sv0);
        sv1 = FDOT2(__builtin_bit_cast(hf2, a4.y), pw[4 * q4 + 1], sv1);
        sv0 = FDOT2(__builtin_bit_cast(hf2, a4.z), pw[4 * q4 + 2], sv0);
        sv1 = FDOT2(__builtin_bit_cast(hf2, a4.w), pw[4 * q4 + 3], sv1);
        se0 = FDOT2(__builtin_bit_cast(hf2, b4.x), pw[4 * q4 + 0], se0);
        se1 = FDOT2(__builtin_bit_cast(hf2, b4.y), pw[4 * q4 + 1], se1);
        se0 = FDOT2(__builtin_bit_cast(hf2, b4.z), pw[4 * q4 + 2], se0);
        se1 = FDOT2(__builtin_bit_cast(hf2, b4.w), pw[4 * q4 + 3], se1);
      }
      {  // tail: ap=32
        float4 a4 = vr4[8];
        float4 b4 = vp4[(size_t)8 * 128];
        sv0 = FDOT2(__builtin_bit_cast(hf2, a4.x), pw[32], sv0);
        se0 = FDOT2(__builtin_bit_cast(hf2, b4.x), pw[32], se0);
      }
      float sv = sv0 + sv1, se = se0 + se1;
      int c2 = g * 16 + c;
      int o0 = 2 * c2;
      float val = og[o0] * RSBN * (sv * inv) + ob[o0]
                + og[o0 + 1] * RSBN * (se * inv) + ob[o0 + 1];
      yT[((size_t)(n * 128 + c2)) * 16384 + w * 128 + i] = val;
    }
  }
}

// ---------- XS: stage yT plane (fp32 LDS), emit xnb (shift+IN, bf16) + yStd (fp32) ----------
__global__ __launch_bounds__(256) void k_xs(const float* __restrict__ yT,
                                            const float* __restrict__ inw,
                                            const float* __restrict__ inb,
                                            short* __restrict__ xnb,
                                            float* __restrict__ yStd) {
  int gid = blockIdx.x;
  int n, cs, cx = -1;
  bool wStd;
  if (gid < 256) {
    n = gid >> 7; cx = gid & 127;
    cs = (cx < 40) ? (cx % 10) : cx;
    wStd = (cx < 10) || (cx >= 40);
  } else {
    int u = gid - 256;
    n = u / 30; cs = 10 + (u % 30);
    wStd = true;
  }
  int dh = 0, dw = 0;
  if (cx >= 0) {
    if (cx < 10)       dw = -2;
    else if (cx < 20)  dw = 2;
    else if (cx < 30)  dh = -2;
    else if (cx < 40)  dh = 2;
  }
  __shared__ float Sb[128 * 130];
  __shared__ float sm[8];
  const float* src = yT + ((size_t)(n * 128 + cs)) * 16384;
  int t = threadIdx.x;
  #pragma unroll
  for (int l = 0; l < 16; ++l) {
    int q = t + l * 256;
    float4 v = *(const float4*)&src[q * 4];
    int w = q >> 5, i0 = (q * 4) & 127;
    float* d = &Sb[w * 130 + i0];
    *(float2*)d = make_float2(v.x, v.y);
    *(float2*)(d + 2) = make_float2(v.z, v.w);
  }
  __syncthreads();
  if (wStd) {
    float* dst = yStd + ((size_t)(n * 128 + cs)) * 16384;
    for (int l = 0; l < 64; ++l) {
      int idx = t + l * 256;
      int h = idx >> 7, w = idx & 127;
      dst[idx] = Sb[w * 130 + h];
    }
  }
  if (cx >= 0) {
    float s = 0.f, q2 = 0.f;
    for (int l = 0; l < 64; ++l) {
      int idx = t + l * 256;
      int h = idx >> 7, w = idx & 127;
      int hs = h + dh, ws = w + dw;
      float v = (hs >= 0 && hs < 128 && ws >= 0 && ws < 128) ? Sb[ws * 130 + hs] : 0.f;
      s += v; q2 += v * v;
    }
    #pragma unroll
    for (int o = 32; o; o >>= 1) { s += __shfl_down(s, o); q2 += __shfl_down(q2, o); }
    if ((t & 63) == 0) { sm[(t >> 6) * 2] = s; sm[(t >> 6) * 2 + 1] = q2; }
    __syncthreads();
    float S_ = sm[0] + sm[2] + sm[4] + sm[6];
    float Q_ = sm[1] + sm[3] + sm[5] + sm[7];
    float mean = S_ * (1.0f / 16384.0f);
    float var = Q_ * (1.0f / 16384.0f) - mean * mean;
    float scale = inw[cx] * rsqrtf(var + 1e-5f);
    float shift = inb[cx] - mean * scale;
    short* dst = xnb + ((size_t)(n * 128 + cx)) * 16384;
    for (int l = 0; l < 64; ++l) {
      int idx = t + l * 256;
      int h = idx >> 7, w = idx & 127;
      int hs = h + dh, ws = w + dw;
      float v = (hs >= 0 && hs < 128 && ws >= 0 && ws < 128) ? Sb[ws * 130 + hs] : 0.f;
      dst[idx] = f2b(v * scale + shift);
    }
  }
}

// ---------- FUSED MLP: out = W2 . gelu(W1 . xn) + yStd; 32-pixel tiles ----------
__global__ __launch_bounds__(256) void k_mlp(
    const short* __restrict__ xnb, const short* __restrict__ w1b,
    const short* __restrict__ w2b, const float* __restrict__ y,
    float* __restrict__ out) {
  const int pb = blockIdx.x * 32;
  const int n = blockIdx.z;
  __shared__ short Asm[128 * 40];
  __shared__ short Bxn[32 * 136];
  __shared__ short h1s[32 * 136];
  const int t = threadIdx.x;
  const int lane = t & 63, wv = t >> 6;
  const int wm = wv >> 1, wn = wv & 1;
  const int lr = lane & 15, lk = (lane >> 4) * 8;
  const short* X = xnb + (size_t)n * 128 * 16384;
  #pragma unroll
  for (int i2 = 0; i2 < 2; ++i2) {
    int u = t + 256 * i2;
    int c = u >> 2, p0 = (u & 3) * 8;
    bf16x8 hv = *(const bf16x8*)&X[(size_t)c * 16384 + pb + p0];
    #pragma unroll
    for (int j = 0; j < 8; ++j) Bxn[(p0 + j) * 136 + c] = hv[j];
  }
  f32x4 acc2[4][1];
  #pragma unroll
  for (int i = 0; i < 4; ++i)
    #pragma unroll
    for (int q = 0; q < 4; ++q) acc2[i][0][q] = 0.f;
  __syncthreads();

  for (int och = 0; och < 4; ++och) {
    f32x4 acc1[4][1];
    #pragma unroll
    for (int i = 0; i < 4; ++i)
      #pragma unroll
      for (int q = 0; q < 4; ++q) acc1[i][0][q] = 0.f;
    for (int c0 = 0; c0 < 128; c0 += 32) {
      #pragma unroll
      for (int i2 = 0; i2 < 2; ++i2) {
        int u = t + 256 * i2;
        int row = u >> 2, kq = (u & 3) * 8;
        *(bf16x8*)&Asm[row * 40 + kq] =
            *(const bf16x8*)&w1b[(och * 128 + row) * 128 + c0 + kq];
      }
      __syncthreads();
      bf16x8 af[4], bfr;
      #pragma unroll
      for (int mf = 0; mf < 4; ++mf)
        af[mf] = *(bf16x8*)&Asm[(wm * 64 + mf * 16 + lr) * 40 + lk];
      bfr = *(bf16x8*)&Bxn[(wn * 16 + lr) * 136 + c0 + lk];
      #pragma unroll
      for (int mf = 0; mf < 4; ++mf)
        acc1[mf][0] = MFMA16(af[mf], bfr, acc1[mf][0]);
      __syncthreads();
    }
    #pragma unroll
    for (int mf = 0; mf < 4; ++mf)
      #pragma unroll
      for (int r = 0; r < 4; ++r) {
        int o = wm * 64 + mf * 16 + (lane >> 4) * 4 + r;
        int p = wn * 16 + lr;
        h1s[p * 136 + o] = f2b(gelu_exact(acc1[mf][0][r]));
      }
    for (int k0 = 0; k0 < 128; k0 += 32) {
      #pragma unroll
      for (int i2 = 0; i2 < 2; ++i2) {
        int u = t + 256 * i2;
        int row = u >> 2, kq = (u & 3) * 8;
        *(bf16x8*)&Asm[row * 40 + kq] =
            *(const bf16x8*)&w2b[row * 512 + och * 128 + k0 + kq];
      }
      __syncthreads();
      bf16x8 af[4], bfr;
      #pragma unroll
      for (int mf = 0; mf < 4; ++mf)
        af[mf] = *(bf16x8*)&Asm[(wm * 64 + mf * 16 + lr) * 40 + lk];
      bfr = *(bf16x8*)&h1s[(wn * 16 + lr) * 136 + k0 + lk];
      #pragma unroll
      for (int mf = 0; mf < 4; ++mf)
        acc2[mf][0] = MFMA16(af[mf], bfr, acc2[mf][0]);
      __syncthreads();
    }
  }
  #pragma unroll
  for (int mf = 0; mf < 4; ++mf)
    #pragma unroll
    for (int r = 0; r < 4; ++r) {
      int o = wm * 64 + mf * 16 + (lane >> 4) * 4 + r;
      int p = pb + wn * 16 + lr;
      size_t base = ((size_t)(n * 128 + o)) * 16384 + p;
      out[base] = acc2[mf][0][r] + y[base];
    }
}

extern "C" void kernel_launch(void* const* d_in, const int* in_sizes, int n_in,
                              void* d_out, int out_size, void* d_ws, size_t ws_size,
                              hipStream_t stream) {
  const float* x        = (const float*)d_in[0];
  const float* w_qkv    = (const float*)d_in[1];
  const float* bn_qkv_g = (const float*)d_in[2];
  const float* bn_qkv_b = (const float*)d_in[3];
  const float* bn_sim_g = (const float*)d_in[4];
  const float* bn_sim_b = (const float*)d_in[5];
  const float* bn_out_g = (const float*)d_in[6];
  const float* bn_out_b = (const float*)d_in[7];
  const float* in_w     = (const float*)d_in[8];
  const float* in_b     = (const float*)d_in[9];
  const float* mlp_w1   = (const float*)d_in[10];
  const float* mlp_w2   = (const float*)d_in[11];
  const float* base_rel = (const float*)d_in[12];
  float* Wp = (float*)d_ws;

  __half* relA2  = (__half*)(Wp + 0);        // 17,680 f
  __half* relAT2 = (__half*)(Wp + 17680);    // 17,680 f
  __half* veA4   = (__half*)(Wp + 35360);    // 147,456 halves = 73,728 f
  float* yT      = Wp + 109088;              // 4,194,304
  float* yStd    = Wp + 4303392;             // 4,194,304
  short* wqb     = (short*)(Wp + 8497696);   // 32,768 shorts
  short* w1b     = (short*)(Wp + 8514080);   // 65,536 shorts
  short* w2b     = (short*)(Wp + 8546848);   // 65,536 shorts
  short* xnb     = (short*)(Wp + 8579616);   // 4,194,304 shorts
  short* qkvT    = (short*)(Wp + 10676768);  // 4,259,840 shorts
  // peak: 12,806,688 floats = 51.2 MB

  k_prep<<<dim3(1097), dim3(256), 0, stream>>>(base_rel, w_qkv, mlp_w1, mlp_w2,
                                               wqb, w1b, w2b, relA2, relAT2, veA4);
  k_qkv_mfma<<<dim3(2, 130, 2), dim3(256), 0, stream>>>(x, wqb, bn_qkv_g, bn_qkv_b, qkvT);
  k_attn<<<dim3(2048), dim3(256), 0, stream>>>(qkvT, relA2, relAT2, veA4,
                                               bn_sim_g, bn_sim_b, bn_out_g, bn_out_b, yT);
  k_xs<<<dim3(316), dim3(256), 0, stream>>>(yT, in_w, in_b, xnb, yStd);
  k_mlp<<<dim3(512, 1, 2), dim3(256), 0, stream>>>(xnb, w1b, w2b, yStd, (float*)d_out);
}